// Round 9
// baseline (17.451 us; speedup 1.0000x reference)
//
#include <hip/hip_runtime.h>

// CTC batch cost, faithful port of the JAX reference (incl. the input_len = C
// source bug). B=512, T=512, C=128, L=64 -> S=129 states, TU=128 time steps.
//
// Round 9 structure: the kernel was MLP-limited (cold-HBM gathers, few
// outstanding loads). Each block now bulk-DMAs its entire 64 KB y_pred slab
// (rows 0..127) into LDS via 64x global_load_lds_dwordx4 -- no VGPR
// destinations, so all ~63 stay in flight and HBM saturates chip-wide
// (512 blocks x 64 KB outstanding). One explicit vmcnt(0) drain, then the
// scaled LINEAR-space recursion (no transcendentals on the chain) runs
// entirely from LDS:
//   nb0 = (b0 + b1p) * pbe          b1p = lane-1's b1 via ONE DPP wave_shr:1
//   nb1 = (b0 + fma(skipf,b1p,b1)) * ple
//   nb2 = (b2 + b1) * pbe           (state 128, lane-63 local)
// Blank col preloaded to 2 VGPRs (readlane broadcast per step, full unroll);
// label probs stream through a 16-deep register ring of ds_reads.
// Every 8 steps: renorm by wave max (DPP butterfly) with exact power-of-2
// scale; exponent accumulates in an int. loss = -ln2*(log2(b1+b2)+acc).

#define BB 512
#define TT 512
#define CC 128
#define LL 64
#define TU 128   // input_len = C (source bug, replicated)
#define EPSF 1e-7f
#define PD 16    // LDS-read ring depth (power of two)
#define LN2F 0.69314718055994530942f

template <int CTRL>
__device__ __forceinline__ float dpp_f(float x) {
    const int xi = __float_as_int(x);
    return __int_as_float(__builtin_amdgcn_update_dpp(xi, xi, CTRL, 0xF, 0xF, false));
}

// whole-wave shift-up-by-1 with zero fill into lane 0: one v_mov_dpp.
__device__ __forceinline__ float shift_up1z(float x) {
    const int xi = __float_as_int(x);
    return __int_as_float(__builtin_amdgcn_update_dpp(xi, xi, 0x138 /*wave_shr:1*/,
                                                      0xF, 0xF, true));
}

// wave-wide max via DPP butterfly; global max in lane 63, broadcast via readlane.
__device__ __forceinline__ float wave_max(float v) {
    v = fmaxf(v, dpp_f<0xB1>(v));   // quad_perm [1,0,3,2]
    v = fmaxf(v, dpp_f<0x4E>(v));   // quad_perm [2,3,0,1]
    v = fmaxf(v, dpp_f<0x141>(v));  // row_half_mirror
    v = fmaxf(v, dpp_f<0x140>(v));  // row_mirror
    v = fmaxf(v, dpp_f<0x142>(v));  // row_bcast15
    v = fmaxf(v, dpp_f<0x143>(v));  // row_bcast31
    return __int_as_float(__builtin_amdgcn_readlane(__float_as_int(v), 63));
}

__device__ __forceinline__ void renorm(float& b0, float& b1, float& b2,
                                       int& acc, int lane, int t_done) {
    float m = fmaxf(b0, b1);
    if (lane == 63) m = fmaxf(m, b2);
    m = (lane + 64 >= t_done) ? m : 0.0f;   // only tail-reachable lanes matter
    const float M = wave_max(m);
    int e = 0;
    (void)frexpf(M, &e);                    // native v_frexp_exp; frexpf(0)->e=0
    const float scale = ldexpf(1.0f, -e);   // exact power of two
    b0 *= scale; b1 *= scale; b2 *= scale;
    acc += e;
}

__global__ __launch_bounds__(64) void ctc_wave(const int* __restrict__ y_true,
                                               const float* __restrict__ y_pred,
                                               float* __restrict__ out) {
    __shared__ float lds[TU * CC];          // 64 KB: rows 0..127 of this batch
    const int b = blockIdx.x;
    const int lane = threadIdx.x;
    const float* yp = y_pred + (size_t)b * TT * CC;

    // Bulk DMA: 64 x 1KB global->LDS, no VGPR destinations (max outstanding).
    {
        auto ldsb = (__attribute__((address_space(3))) unsigned int*)lds;
        auto gb   = (const __attribute__((address_space(1))) unsigned int*)yp;
#pragma unroll
        for (int i = 0; i < 64; ++i) {
            // lane l -> global byte i*1024 + l*16, LDS byte i*1024 + l*16
            __builtin_amdgcn_global_load_lds(gb + i * 256 + lane * 4,
                                             ldsb + i * 256, 16, 0, 0);
        }
    }

    const int lbl  = y_true[b * LL + lane];   // label for state 2*lane+1
    const int lblp = __shfl_up(lbl, 1);       // one-time, off the hot loop
    const float skipf = (lane >= 1 && lbl != lblp) ? 1.0f : 0.0f;

    asm volatile("s_waitcnt vmcnt(0)" ::: "memory");   // DMA drain (single point)

    // Blank column (lane-uniform per t), pre-eps'd, register-resident.
    const float pbr0e = lds[lane * CC + (CC - 1)] + EPSF;
    const float pbr1e = lds[(64 + lane) * CC + (CC - 1)] + EPSF;

    // Label-prob ring for t = 1..PD from LDS.
    float plr[PD];
#pragma unroll
    for (int j = 0; j < PD; ++j) plr[j] = lds[(1 + j) * CC + lbl];

    // t = 0 init (linear space): states 0,1 = p + eps; everything else 0.
    const float pl0 = lds[lbl] + EPSF;
    const float pb0 = __int_as_float(__builtin_amdgcn_readlane(__float_as_int(pbr0e), 0));
    float b0 = (lane == 0) ? pb0 : 0.0f;
    float b1 = (lane == 0) ? pl0 : 0.0f;
    float b2 = 0.0f;
    int acc = 0;

#pragma unroll
    for (int t = 1; t < TU; ++t) {
        const int slot = (t - 1) & (PD - 1);       // compile-time under unroll
        const float plv = plr[slot];
        const int trow = (t + PD < TU) ? (t + PD) : (TU - 1);  // clamp, dead past end
        plr[slot] = lds[trow * CC + lbl];          // refill for step t+PD
        const float ple = plv + EPSF;
        const float pbe = __int_as_float(__builtin_amdgcn_readlane(
            __float_as_int((t < 64) ? pbr0e : pbr1e), t & 63));
        const float b1p = shift_up1z(b1);
        const float nb0 = (b0 + b1p) * pbe;
        const float h   = __builtin_fmaf(skipf, b1p, b1);
        const float nb1 = (b0 + h) * ple;
        const float nb2 = (b2 + b1) * pbe;
        b0 = nb0; b1 = nb1; b2 = nb2;
        if ((t & 7) == 0) renorm(b0, b1, b2, acc, lane, t);
    }

    if (lane == 63) {
        const float s = b1 + b2;                   // states 127, 128
        out[b] = -LN2F * (__log2f(s) + (float)acc);
    }
}

extern "C" void kernel_launch(void* const* d_in, const int* in_sizes, int n_in,
                              void* d_out, int out_size, void* d_ws, size_t ws_size,
                              hipStream_t stream) {
    const int*   y_true = (const int*)d_in[0];
    const float* y_pred = (const float*)d_in[1];
    float*       out    = (float*)d_out;
    (void)in_sizes; (void)n_in; (void)out_size; (void)d_ws; (void)ws_size;

    ctc_wave<<<BB, 64, 0, stream>>>(y_true, y_pred, out);
}

// Round 10
// 11.449 us; speedup vs baseline: 1.5243x; 1.5243x over previous
//
#include <hip/hip_runtime.h>

// CTC batch cost, faithful port of the JAX reference (incl. the input_len = C
// source bug). B=512, T=512, C=128, L=64 -> S=129 states, TU=128 time steps.
//
// Round 10 structure: r9's single-wave LDS-DMA couldn't fill the memory
// pipeline (2 waves/CU, full drain). Now: one block of 8 WAVES (512 thr) per
// batch. All 8 waves cooperatively DMA the 64 KB y_pred slab into LDS
// (8 x 1KB global_load_lds each, no VGPR destinations), drain their own
// vmcnt, barrier once; wave 0 then runs the serial recursion from LDS while
// waves 1-7 exit. 16 waves/CU issue DMA concurrently -> HBM-saturating MLP.
//
// Recursion (scaled LINEAR space, no transcendentals on the chain):
//   nb0 = (b0 + b1p) * pbe          b1p = lane-1's b1 via ONE DPP wave_shr:1
//   nb1 = (b0 + fma(skipf,b1p,b1)) * ple
//   nb2 = (b2 + b1) * pbe           (state 128, lane-63 local)
// Blank col pre-eps'd in 2 VGPRs (readlane broadcast, full unroll); label
// probs stream through a 16-deep ds_read register ring. Every 8 steps:
// renorm by wave max (DPP butterfly) with an exact power-of-2 scale;
// exponent accumulates in an int. loss = -ln2*(log2(b1+b2)+acc) at lane 63.

#define BB 512
#define TT 512
#define CC 128
#define LL 64
#define TU 128   // input_len = C (source bug, replicated)
#define EPSF 1e-7f
#define PD 16    // LDS-read ring depth (power of two)
#define LN2F 0.69314718055994530942f
#define NWAVE 8

template <int CTRL>
__device__ __forceinline__ float dpp_f(float x) {
    const int xi = __float_as_int(x);
    return __int_as_float(__builtin_amdgcn_update_dpp(xi, xi, CTRL, 0xF, 0xF, false));
}

// whole-wave shift-up-by-1 with zero fill into lane 0: one v_mov_dpp.
__device__ __forceinline__ float shift_up1z(float x) {
    const int xi = __float_as_int(x);
    return __int_as_float(__builtin_amdgcn_update_dpp(xi, xi, 0x138 /*wave_shr:1*/,
                                                      0xF, 0xF, true));
}

// wave-wide max via DPP butterfly; global max in lane 63, broadcast via readlane.
__device__ __forceinline__ float wave_max(float v) {
    v = fmaxf(v, dpp_f<0xB1>(v));   // quad_perm [1,0,3,2]
    v = fmaxf(v, dpp_f<0x4E>(v));   // quad_perm [2,3,0,1]
    v = fmaxf(v, dpp_f<0x141>(v));  // row_half_mirror
    v = fmaxf(v, dpp_f<0x140>(v));  // row_mirror
    v = fmaxf(v, dpp_f<0x142>(v));  // row_bcast15
    v = fmaxf(v, dpp_f<0x143>(v));  // row_bcast31
    return __int_as_float(__builtin_amdgcn_readlane(__float_as_int(v), 63));
}

__device__ __forceinline__ void renorm(float& b0, float& b1, float& b2,
                                       int& acc, int lane, int t_done) {
    float m = fmaxf(b0, b1);
    if (lane == 63) m = fmaxf(m, b2);
    m = (lane + 64 >= t_done) ? m : 0.0f;   // only tail-reachable lanes matter
    const float M = wave_max(m);
    int e = 0;
    (void)frexpf(M, &e);                    // native v_frexp_exp; frexpf(0)->e=0
    const float scale = ldexpf(1.0f, -e);   // exact power of two
    b0 *= scale; b1 *= scale; b2 *= scale;
    acc += e;
}

__global__ __launch_bounds__(NWAVE * 64) void ctc_wave(const int* __restrict__ y_true,
                                                       const float* __restrict__ y_pred,
                                                       float* __restrict__ out) {
    __shared__ float lds[TU * CC];          // 64 KB: rows 0..127 of this batch
    const int b = blockIdx.x;
    const int tid = threadIdx.x;
    const int wid = tid >> 6;
    const int lane = tid & 63;
    const float* yp = y_pred + (size_t)b * TT * CC;

    // Cooperative DMA: 64 x 1KB global->LDS spread over 8 waves (8 each),
    // no VGPR destinations. Each wave drains its own vmcnt, then one barrier
    // guarantees the whole 64 KB slab is resident.
    {
        auto ldsb = (__attribute__((address_space(3))) unsigned int*)lds;
        auto gb   = (const __attribute__((address_space(1))) unsigned int*)yp;
#pragma unroll
        for (int r = 0; r < 64 / NWAVE; ++r) {
            const int i = wid * (64 / NWAVE) + r;   // 1KB chunk index
            __builtin_amdgcn_global_load_lds(gb + i * 256 + lane * 4,
                                             ldsb + i * 256, 16, 0, 0);
        }
    }
    asm volatile("s_waitcnt vmcnt(0)" ::: "memory");
    __syncthreads();
    if (wid != 0) return;                   // waves 1-7 were DMA-only

    const int lbl  = y_true[b * LL + lane];   // label for state 2*lane+1
    const int lblp = __shfl_up(lbl, 1);       // one-time, off the hot loop
    const float skipf = (lane >= 1 && lbl != lblp) ? 1.0f : 0.0f;

    // Blank column (lane-uniform per t), pre-eps'd, register-resident.
    const float pbr0e = lds[lane * CC + (CC - 1)] + EPSF;
    const float pbr1e = lds[(64 + lane) * CC + (CC - 1)] + EPSF;

    // Label-prob ring for t = 1..PD from LDS.
    float plr[PD];
#pragma unroll
    for (int j = 0; j < PD; ++j) plr[j] = lds[(1 + j) * CC + lbl];

    // t = 0 init (linear space): states 0,1 = p + eps; everything else 0.
    const float pl0 = lds[lbl] + EPSF;
    const float pb0 = __int_as_float(__builtin_amdgcn_readlane(__float_as_int(pbr0e), 0));
    float b0 = (lane == 0) ? pb0 : 0.0f;
    float b1 = (lane == 0) ? pl0 : 0.0f;
    float b2 = 0.0f;
    int acc = 0;

#pragma unroll
    for (int t = 1; t < TU; ++t) {
        const int slot = (t - 1) & (PD - 1);       // compile-time under unroll
        const float plv = plr[slot];
        const int trow = (t + PD < TU) ? (t + PD) : (TU - 1);  // clamp, dead past end
        plr[slot] = lds[trow * CC + lbl];          // refill for step t+PD
        const float ple = plv + EPSF;
        const float pbe = __int_as_float(__builtin_amdgcn_readlane(
            __float_as_int((t < 64) ? pbr0e : pbr1e), t & 63));
        const float b1p = shift_up1z(b1);
        const float nb0 = (b0 + b1p) * pbe;
        const float h   = __builtin_fmaf(skipf, b1p, b1);
        const float nb1 = (b0 + h) * ple;
        const float nb2 = (b2 + b1) * pbe;
        b0 = nb0; b1 = nb1; b2 = nb2;
        if ((t & 7) == 0) renorm(b0, b1, b2, acc, lane, t);
    }

    if (lane == 63) {
        const float s = b1 + b2;                   // states 127, 128
        out[b] = -LN2F * (__log2f(s) + (float)acc);
    }
}

extern "C" void kernel_launch(void* const* d_in, const int* in_sizes, int n_in,
                              void* d_out, int out_size, void* d_ws, size_t ws_size,
                              hipStream_t stream) {
    const int*   y_true = (const int*)d_in[0];
    const float* y_pred = (const float*)d_in[1];
    float*       out    = (float*)d_out;
    (void)in_sizes; (void)n_in; (void)out_size; (void)d_ws; (void)ws_size;

    ctc_wave<<<BB, NWAVE * 64, 0, stream>>>(y_true, y_pred, out);
}